// Round 3
// baseline (267.656 us; speedup 1.0000x reference)
//
#include <hip/hip_runtime.h>

// Problem constants (fixed by setup_inputs in the reference)
constexpr int B = 128;
constexpr int C = 4;          // classes; C*S = 2^18
constexpr int S = 65536;      // 2^16
constexpr int N = B * S;      // 8388608 positions
constexpr int NG = N / 4;     // float4 groups = 2097152
constexpr int NSEG = 8;
// 16 accumulators: 8 per-segment loss sums, 8 per-segment valid counts.
// sum(mask) == sum of counts; mean(loss) numerator == sum of loss sums.
constexpr int NACC = 2 * NSEG;

constexpr int GRID = 8192;
constexpr int BLOCK = 256;
static_assert(GRID * BLOCK == NG, "one float4 group per thread");

// ws layout: pt[i * GRID + b] = block b's partial for accumulator i
// (column-major so stage-2 reads coalesce). 8192*16*4 = 512 KB.

__global__ __launch_bounds__(BLOCK) void ce_partial_kernel(
    const float* __restrict__ input,   // (B, C, S)
    const int*   __restrict__ target,  // (B, S) values in [0, C)
    const int*   __restrict__ seg,     // (B, S) values in [0, NSEG)
    const float* __restrict__ mask,    // (B, S) in {0,1}
    float* __restrict__ pt)            // (NACC, GRID) partials
{
    const int g = blockIdx.x * BLOCK + threadIdx.x;  // one float4 group
    const int p = g << 2;             // flat position (b*S + s), 4-aligned
    const int b = p >> 16;            // p / S
    const int s = p & (S - 1);
    const int base = (b << 18) + s;   // b*C*S + s

    // 7 independent 16B loads — all issued before any use (max MLP)
    const float4 l0 = *(const float4*)(input + base);
    const float4 l1 = *(const float4*)(input + base + S);
    const float4 l2 = *(const float4*)(input + base + 2 * S);
    const float4 l3 = *(const float4*)(input + base + 3 * S);
    const int4   tg = *(const int4*)(target + p);
    const int4   sv = *(const int4*)(seg + p);
    const float4 mk = *(const float4*)(mask + p);

    float ssum[NSEG], scnt[NSEG];
#pragma unroll
    for (int k = 0; k < NSEG; ++k) { ssum[k] = 0.f; scnt[k] = 0.f; }

    const float a0[4] = { l0.x, l0.y, l0.z, l0.w };
    const float a1[4] = { l1.x, l1.y, l1.z, l1.w };
    const float a2[4] = { l2.x, l2.y, l2.z, l2.w };
    const float a3[4] = { l3.x, l3.y, l3.z, l3.w };
    const int   tgv[4] = { tg.x, tg.y, tg.z, tg.w };
    const int   sgv[4] = { sv.x, sv.y, sv.z, sv.w };
    const float mkv[4] = { mk.x, mk.y, mk.z, mk.w };

#pragma unroll
    for (int j = 0; j < 4; ++j) {
        const float x0 = a0[j], x1 = a1[j], x2 = a2[j], x3 = a3[j];
        const float m = fmaxf(fmaxf(x0, x1), fmaxf(x2, x3));
        const float sum = __expf(x0 - m) + __expf(x1 - m)
                        + __expf(x2 - m) + __expf(x3 - m);
        const float lse = m + __logf(sum);
        const int t = tgv[j];
        const float chosen = (t == 0) ? x0 : (t == 1) ? x1 : (t == 2) ? x2 : x3;
        const float mval = mkv[j];
        const float loss = (lse - chosen) * mval;   // ce * mask (mask ∈ {0,1})
        const int sgj = sgv[j];
        // Predicated accumulation (no dynamic register indexing).
        // valid == mask since mask ∈ {0,1}.
#pragma unroll
        for (int k = 0; k < NSEG; ++k) {
            const bool hit = (sgj == k);
            ssum[k] += hit ? loss : 0.f;
            scnt[k] += hit ? mval : 0.f;
        }
    }

    // Wave (64-lane) butterfly reduction of the 16 accumulators
    float vals[NACC];
#pragma unroll
    for (int k = 0; k < NSEG; ++k) { vals[k] = ssum[k]; vals[NSEG + k] = scnt[k]; }
#pragma unroll
    for (int i = 0; i < NACC; ++i) {
        float v = vals[i];
#pragma unroll
        for (int off = 32; off > 0; off >>= 1)
            v += __shfl_xor(v, off, 64);
        vals[i] = v;
    }

    __shared__ float red[4][NACC];
    const int wave = threadIdx.x >> 6;
    const int lane = threadIdx.x & 63;
    if (lane == 0) {
#pragma unroll
        for (int i = 0; i < NACC; ++i) red[wave][i] = vals[i];
    }
    __syncthreads();
    // 16 plain stores per block to private slots — no atomics
    if (threadIdx.x < NACC) {
        const int i = threadIdx.x;
        pt[i * GRID + blockIdx.x] =
            red[0][i] + red[1][i] + red[2][i] + red[3][i];
    }
}

// Stage 2: reduce (NACC, GRID) partials and run the scalar epilogue. One block.
__global__ __launch_bounds__(1024) void ce_final_kernel(
    const float* __restrict__ pt, float* __restrict__ out)
{
    const int t = threadIdx.x;            // 1024 threads
    float vals[NACC];
#pragma unroll
    for (int i = 0; i < NACC; ++i) {
        float v = 0.f;
#pragma unroll
        for (int k = 0; k < GRID / 1024; ++k)      // 8 coalesced strips
            v += pt[i * GRID + t + k * 1024];
#pragma unroll
        for (int off = 32; off > 0; off >>= 1)
            v += __shfl_xor(v, off, 64);
        vals[i] = v;
    }

    __shared__ float red[16][NACC];
    const int wave = t >> 6;
    const int lane = t & 63;
    if (lane == 0) {
#pragma unroll
        for (int i = 0; i < NACC; ++i) red[wave][i] = vals[i];
    }
    __syncthreads();

    if (t == 0) {
        float acc[NACC];
        for (int i = 0; i < NACC; ++i) {
            float v = 0.f;
            for (int w = 0; w < 16; ++w) v += red[w][i];
            acc[i] = v;
        }

        float ssum[NSEG], scnt[NSEG];
        float tot_loss = 0.f, msum = 0.f;
        for (int k = 0; k < NSEG; ++k) {
            ssum[k] = acc[k];
            scnt[k] = acc[NSEG + k];
            tot_loss += ssum[k];
            msum += scnt[k];                       // sum(mask) == sum of counts
        }
        const float fallback = tot_loss / (float)N;   // jnp.mean(loss)

        float cl[NSEG], cc[NSEG];
        float total = 0.f;
        for (int k = 0; k < NSEG; ++k) {
            const bool has = scnt[k] > 0.f;
            cl[k] = has ? (ssum[k] / scnt[k]) : fallback;
            cc[k] = has ? scnt[k] : 1.f;
            total += cl[k] * cc[k];
        }
        float num = 0.f;
        for (int k = 0; k < NSEG; ++k) {
            const float prop = (total > 0.f) ? (cl[k] * cc[k] / total)
                                             : (1.f / (float)NSEG);
            const float w = 1.f + prop;               // WEIGHT_ALPHA = 1.0
            // sum(loss * adaptive_weights) = sum_k w[k] * seg_sum[k]
            num += w * ssum[k];
        }
        out[0] = num / msum;                          // / sum(mask)
    }
}

extern "C" void kernel_launch(void* const* d_in, const int* in_sizes, int n_in,
                              void* d_out, int out_size, void* d_ws, size_t ws_size,
                              hipStream_t stream) {
    const float* input  = (const float*)d_in[0];
    const int*   target = (const int*)d_in[1];
    const int*   seg    = (const int*)d_in[2];
    const float* mask   = (const float*)d_in[3];
    float* pt  = (float*)d_ws;            // NACC * GRID floats = 512 KB
    float* out = (float*)d_out;

    ce_partial_kernel<<<GRID, BLOCK, 0, stream>>>(input, target, seg, mask, pt);
    ce_final_kernel<<<1, 1024, 0, stream>>>(pt, out);
}

// Round 5
// 246.756 us; speedup vs baseline: 1.0847x; 1.0847x over previous
//
#include <hip/hip_runtime.h>

// Problem constants (fixed by setup_inputs in the reference)
constexpr int B = 128;
constexpr int C = 4;          // classes; C*S = 2^18
constexpr int S = 65536;      // 2^16
constexpr int N = B * S;      // 8388608 positions
constexpr int NG = N / 4;     // float4 groups = 2097152
constexpr int NSEG = 8;
constexpr int NACC = 2 * NSEG;   // 8 seg loss-sums + 8 seg counts

constexpr int GRID = 1024;
constexpr int BLOCK = 256;
constexpr int ITERS = 8;
static_assert(GRID * BLOCK * ITERS == NG, "exact tiling");

// Native Clang vector types — accepted by __builtin_nontemporal_load
// (HIP_vector_type float4/int4 are structs and are rejected).
typedef float fx4 __attribute__((ext_vector_type(4)));
typedef int   ix4 __attribute__((ext_vector_type(4)));

// One float4-group of 4 consecutive positions
struct Grp {
    fx4 l0, l1, l2, l3;   // logits, classes 0..3
    ix4 tg, sv;           // target, segment
    fx4 mk;               // mask
};

__device__ __forceinline__ Grp load_grp(
    const float* __restrict__ input, const int* __restrict__ target,
    const int* __restrict__ seg, const float* __restrict__ mask, int g)
{
    const int p = g << 2;             // flat position (b*S + s), 4-aligned
    const int b = p >> 16;            // p / S
    const int s = p & (S - 1);
    const int base = (b << 18) + s;   // b*C*S + s
    Grp r;
    // Non-temporal: read-once streams, don't churn L1/L2 allocation
    r.l0 = __builtin_nontemporal_load((const fx4*)(input + base));
    r.l1 = __builtin_nontemporal_load((const fx4*)(input + base + S));
    r.l2 = __builtin_nontemporal_load((const fx4*)(input + base + 2 * S));
    r.l3 = __builtin_nontemporal_load((const fx4*)(input + base + 3 * S));
    r.tg = __builtin_nontemporal_load((const ix4*)(target + p));
    r.sv = __builtin_nontemporal_load((const ix4*)(seg + p));
    r.mk = __builtin_nontemporal_load((const fx4*)(mask + p));
    return r;
}

__global__ __launch_bounds__(BLOCK) void ce_partial_kernel(
    const float* __restrict__ input,   // (B, C, S)
    const int*   __restrict__ target,  // (B, S) in [0, C)
    const int*   __restrict__ seg,     // (B, S) in [0, NSEG)
    const float* __restrict__ mask,    // (B, S) in {0,1}
    float* __restrict__ pt)            // (NACC, GRID) partials
{
    float ssum[NSEG], scnt[NSEG];
#pragma unroll
    for (int k = 0; k < NSEG; ++k) { ssum[k] = 0.f; scnt[k] = 0.f; }

    const int g0 = blockIdx.x * BLOCK + threadIdx.x;
    constexpr int STEP = GRID * BLOCK;

    // Depth-2 software pipeline: iteration k+1's 7 loads are in flight
    // while iteration k is consumed. #pragma unroll 1 keeps exactly 2 buffers.
    Grp cur = load_grp(input, target, seg, mask, g0);
#pragma unroll 1
    for (int it = 0; it < ITERS; ++it) {
        Grp nxt;
        if (it + 1 < ITERS)
            nxt = load_grp(input, target, seg, mask, g0 + (it + 1) * STEP);

        const float a0[4] = { cur.l0.x, cur.l0.y, cur.l0.z, cur.l0.w };
        const float a1[4] = { cur.l1.x, cur.l1.y, cur.l1.z, cur.l1.w };
        const float a2[4] = { cur.l2.x, cur.l2.y, cur.l2.z, cur.l2.w };
        const float a3[4] = { cur.l3.x, cur.l3.y, cur.l3.z, cur.l3.w };
        const int   tgv[4] = { cur.tg.x, cur.tg.y, cur.tg.z, cur.tg.w };
        const int   sgv[4] = { cur.sv.x, cur.sv.y, cur.sv.z, cur.sv.w };
        const float mkv[4] = { cur.mk.x, cur.mk.y, cur.mk.z, cur.mk.w };

#pragma unroll
        for (int j = 0; j < 4; ++j) {
            const float x0 = a0[j], x1 = a1[j], x2 = a2[j], x3 = a3[j];
            const float m = fmaxf(fmaxf(x0, x1), fmaxf(x2, x3));
            const float sum = __expf(x0 - m) + __expf(x1 - m)
                            + __expf(x2 - m) + __expf(x3 - m);
            const float lse = m + __logf(sum);
            const int t = tgv[j];
            const float chosen = (t == 0) ? x0 : (t == 1) ? x1 : (t == 2) ? x2 : x3;
            const float mval = mkv[j];
            const float loss = (lse - chosen) * mval;   // ce * mask (mask ∈ {0,1})
            const int sgj = sgv[j];
            // Predicated accumulation; valid == mask since mask ∈ {0,1}
#pragma unroll
            for (int k = 0; k < NSEG; ++k) {
                const bool hit = (sgj == k);
                ssum[k] += hit ? loss : 0.f;
                scnt[k] += hit ? mval : 0.f;
            }
        }
        cur = nxt;
    }

    // Wave (64-lane) butterfly reduction of the 16 accumulators
    float vals[NACC];
#pragma unroll
    for (int k = 0; k < NSEG; ++k) { vals[k] = ssum[k]; vals[NSEG + k] = scnt[k]; }
#pragma unroll
    for (int i = 0; i < NACC; ++i) {
        float v = vals[i];
#pragma unroll
        for (int off = 32; off > 0; off >>= 1)
            v += __shfl_xor(v, off, 64);
        vals[i] = v;
    }

    __shared__ float red[4][NACC];
    const int wave = threadIdx.x >> 6;
    const int lane = threadIdx.x & 63;
    if (lane == 0) {
#pragma unroll
        for (int i = 0; i < NACC; ++i) red[wave][i] = vals[i];
    }
    __syncthreads();
    if (threadIdx.x < NACC) {
        const int i = threadIdx.x;
        pt[i * GRID + blockIdx.x] =
            red[0][i] + red[1][i] + red[2][i] + red[3][i];
    }
}

// Stage 2: reduce (NACC, GRID) partials + scalar epilogue. One block.
__global__ __launch_bounds__(1024) void ce_final_kernel(
    const float* __restrict__ pt, float* __restrict__ out)
{
    const int t = threadIdx.x;            // 1024 threads
    float vals[NACC];
#pragma unroll
    for (int i = 0; i < NACC; ++i) {
        float v = pt[i * GRID + t];       // GRID == 1024: one strip
#pragma unroll
        for (int off = 32; off > 0; off >>= 1)
            v += __shfl_xor(v, off, 64);
        vals[i] = v;
    }

    __shared__ float red[16][NACC];
    const int wave = t >> 6;
    const int lane = t & 63;
    if (lane == 0) {
#pragma unroll
        for (int i = 0; i < NACC; ++i) red[wave][i] = vals[i];
    }
    __syncthreads();

    if (t == 0) {
        float acc[NACC];
        for (int i = 0; i < NACC; ++i) {
            float v = 0.f;
            for (int w = 0; w < 16; ++w) v += red[w][i];
            acc[i] = v;
        }

        float ssum[NSEG], scnt[NSEG];
        float tot_loss = 0.f, msum = 0.f;
        for (int k = 0; k < NSEG; ++k) {
            ssum[k] = acc[k];
            scnt[k] = acc[NSEG + k];
            tot_loss += ssum[k];
            msum += scnt[k];                       // sum(mask) == sum of counts
        }
        const float fallback = tot_loss / (float)N;   // jnp.mean(loss)

        float cl[NSEG], cc[NSEG];
        float total = 0.f;
        for (int k = 0; k < NSEG; ++k) {
            const bool has = scnt[k] > 0.f;
            cl[k] = has ? (ssum[k] / scnt[k]) : fallback;
            cc[k] = has ? scnt[k] : 1.f;
            total += cl[k] * cc[k];
        }
        float num = 0.f;
        for (int k = 0; k < NSEG; ++k) {
            const float prop = (total > 0.f) ? (cl[k] * cc[k] / total)
                                             : (1.f / (float)NSEG);
            const float w = 1.f + prop;               // WEIGHT_ALPHA = 1.0
            num += w * ssum[k];   // sum(loss*w) = sum_k w[k]*seg_sum[k]
        }
        out[0] = num / msum;                          // / sum(mask)
    }
}

extern "C" void kernel_launch(void* const* d_in, const int* in_sizes, int n_in,
                              void* d_out, int out_size, void* d_ws, size_t ws_size,
                              hipStream_t stream) {
    const float* input  = (const float*)d_in[0];
    const int*   target = (const int*)d_in[1];
    const int*   seg    = (const int*)d_in[2];
    const float* mask   = (const float*)d_in[3];
    float* pt  = (float*)d_ws;            // NACC * GRID floats = 64 KB
    float* out = (float*)d_out;

    ce_partial_kernel<<<GRID, BLOCK, 0, stream>>>(input, target, seg, mask, pt);
    ce_final_kernel<<<1, 1024, 0, stream>>>(pt, out);
}